// Round 1
// 828.738 us; speedup vs baseline: 1.0860x; 1.0860x over previous
//
#include <hip/hip_runtime.h>
#include <hip/hip_bf16.h>
#include <cstdint>

#define T_DIM 2048
#define B_DIM 16
#define D_DIM 1024
#define N3    (3*D_DIM)          // 3072
#define M_ROWS (T_DIM*B_DIM)     // 32768
#define HALF  (D_DIM/2)          // 512
#define SEG    32
#define SEGLEN (T_DIM/SEG)       // 64
#define NSEQ  (2*B_DIM*HALF)     // 16384
#define NBLK  (N3/128)           // 24 column-blocks in GEMM grid.y

typedef __attribute__((ext_vector_type(8))) short bf16x8;
typedef __attribute__((ext_vector_type(4))) float f32x4;

#define GLD_LDS16(g, l) __builtin_amdgcn_global_load_lds( \
    (const __attribute__((address_space(1))) void*)(g),   \
    (__attribute__((address_space(3))) void*)(l), 16, 0, 0)

__device__ __forceinline__ ushort f2bf(float x) {
    __hip_bfloat16 h = __float2bfloat16(x);
    return *reinterpret_cast<ushort*>(&h);
}

__device__ __forceinline__ float sigmoidf(float x) {
    return 1.0f / (1.0f + __expf(-x));
}

// ---------------- cast input (fp32 -> bf16), 8 elems/thread ----------------
__global__ __launch_bounds__(256) void cast_a(const float* __restrict__ in,
                                              ushort* __restrict__ out) {
    const size_t i = (size_t)blockIdx.x * 256 + threadIdx.x; // handles 8 elems
    const float4* p = (const float4*)in + i * 2;
    float4 a = p[0], b = p[1];
    float f[8] = {a.x, a.y, a.z, a.w, b.x, b.y, b.z, b.w};
    ushort r[8];
#pragma unroll
    for (int j = 0; j < 8; ++j) r[j] = f2bf(f[j]);
    *(uint4*)(out + i * 8) = *(const uint4*)r;
}

// ---------------- W (1024 x 3072) -> W^T (3072 x 1024) bf16 ----------------
__global__ __launch_bounds__(256) void transpose_cast(const float* __restrict__ W,
                                                      ushort* __restrict__ WT) {
    __shared__ float tile[64][65];
    const int c0 = blockIdx.x * 64;  // N dim of W
    const int r0 = blockIdx.y * 64;  // K dim of W
    const int tr = threadIdx.x >> 6; // 0..3
    const int tc = threadIdx.x & 63;
#pragma unroll
    for (int i = 0; i < 16; ++i) {
        const int r = tr + i * 4;
        tile[r][tc] = W[(size_t)(r0 + r) * N3 + c0 + tc];
    }
    __syncthreads();
#pragma unroll
    for (int i = 0; i < 16; ++i) {
        const int r = tr + i * 4;  // row of WT = col of W
        WT[(size_t)(c0 + r) * D_DIM + r0 + tc] = f2bf(tile[tc][r]);
    }
}

// ---------------- GEMM: C(32768x3072) = A(32768x1024) * B, BT is N x K -----
// LDS layout XOR-swizzled (see prior rounds). NEW: epilogue reduces each
// block's 128x128 tile to per-row partial (sum, sumsq) over its 128 columns
// and writes them to `partial[blockIdx.y][row]` — this replaces the whole
// ln_gates read-modify-write pass (768 MB of HBM traffic) with a 6 MB
// deterministic partial buffer.
__global__ __launch_bounds__(256) void gemm_bf16(const ushort* __restrict__ A,
                                                 const ushort* __restrict__ BT,
                                                 float* __restrict__ C,
                                                 float2* __restrict__ partial) {
    const int K = D_DIM;
    const int N = N3;
    __shared__ ushort As[128 * 64];
    __shared__ ushort Bs[128 * 64];
    const int tid  = threadIdx.x;
    const int wave = tid >> 6;
    const int lane = tid & 63;
    const int m0 = blockIdx.x * 128;
    const int n0 = blockIdx.y * 128;
    const int wm = wave >> 1;
    const int wn = wave & 1;

    f32x4 acc[4][4] = {};

    const int srow = lane >> 3;                         // row within 8-row group
    const int skc  = (((lane & 7) ^ (srow & 7)) * 8);   // swizzled k-chunk (elems)

    for (int k0 = 0; k0 < K; k0 += 64) {
#pragma unroll
        for (int it = 0; it < 4; ++it) {
            const int rb = it * 32 + wave * 8;
            GLD_LDS16(A  + (size_t)(m0 + rb + srow) * K + k0 + skc, &As[rb * 64]);
            GLD_LDS16(BT + (size_t)(n0 + rb + srow) * K + k0 + skc, &Bs[rb * 64]);
        }
        __syncthreads();
        const int q  = lane >> 4;
        const int lm = lane & 15;
        const int sw = lm & 7;                          // == row&7 for all frags
#pragma unroll
        for (int kk = 0; kk < 2; ++kk) {
            const int ch = ((kk * 4 + q) ^ sw) * 8;     // swizzled chunk offset
            bf16x8 af[4], bfr[4];
#pragma unroll
            for (int i = 0; i < 4; ++i) {
                af[i]  = *(const bf16x8*)&As[(wm * 64 + i * 16 + lm) * 64 + ch];
                bfr[i] = *(const bf16x8*)&Bs[(wn * 64 + i * 16 + lm) * 64 + ch];
            }
#pragma unroll
            for (int i = 0; i < 4; ++i)
#pragma unroll
                for (int j = 0; j < 4; ++j)
                    acc[i][j] = __builtin_amdgcn_mfma_f32_16x16x32_bf16(af[i], bfr[j], acc[i][j], 0, 0, 0);
        }
        __syncthreads();
    }

    const int q  = lane >> 4;
    const int lm = lane & 15;
#pragma unroll
    for (int i = 0; i < 4; ++i) {
        const int row = m0 + wm * 64 + i * 16 + q * 4;
#pragma unroll
        for (int j = 0; j < 4; ++j) {
            const int col = n0 + wn * 64 + j * 16 + lm;
            float* cp = C + (size_t)row * N + col;
#pragma unroll
            for (int r = 0; r < 4; ++r)
                cp[(size_t)r * N] = acc[i][j][r];
        }
    }

    // ---- per-row partial stats over this block's 128 columns ----
    // All waves are past the K-loop's final barrier, so As is dead; reuse it.
    float* sS  = (float*)&As[0];   // [wn][128] row-sums
    float* sSS = sS + 256;         // [wn][128] row-sumsq
#pragma unroll
    for (int i = 0; i < 4; ++i) {
#pragma unroll
        for (int r = 0; r < 4; ++r) {
            float s  = acc[i][0][r] + acc[i][1][r] + acc[i][2][r] + acc[i][3][r];
            float ss = acc[i][0][r] * acc[i][0][r] + acc[i][1][r] * acc[i][1][r]
                     + acc[i][2][r] * acc[i][2][r] + acc[i][3][r] * acc[i][3][r];
            // reduce across the 16 lm lanes (same rows, different cols)
            s  += __shfl_xor(s, 1);  ss += __shfl_xor(ss, 1);
            s  += __shfl_xor(s, 2);  ss += __shfl_xor(ss, 2);
            s  += __shfl_xor(s, 4);  ss += __shfl_xor(ss, 4);
            s  += __shfl_xor(s, 8);  ss += __shfl_xor(ss, 8);
            if (lm == 0) {
                const int rl = wm * 64 + i * 16 + q * 4 + r;
                sS [wn * 128 + rl] = s;
                sSS[wn * 128 + rl] = ss;
            }
        }
    }
    __syncthreads();
    if (tid < 128) {
        const float S  = sS[tid]  + sS[128 + tid];
        const float SS = sSS[tid] + sSS[128 + tid];
        partial[(size_t)blockIdx.y * M_ROWS + m0 + tid] = make_float2(S, SS);
    }
}

// ---- combine 24 column-block partials -> per-row (mu, rstd) ---------------
__global__ __launch_bounds__(256) void finalize_stats(const float2* __restrict__ partial,
                                                      float2* __restrict__ stats) {
    const int row = blockIdx.x * 256 + threadIdx.x;
    float S = 0.f, SS = 0.f;
#pragma unroll
    for (int nb = 0; nb < NBLK; ++nb) {
        const float2 p = partial[(size_t)nb * M_ROWS + row];
        S += p.x; SS += p.y;
    }
    const float mu  = S * (1.0f / 3072.0f);
    const float var = SS * (1.0f / 3072.0f) - mu * mu;
    stats[row] = make_float2(mu, rsqrtf(var + 1e-5f));
}

// ---------------- segmented linear-recurrence scan -------------------------
// grid: (2, SEG, 32): x = channel chunk, y = segment, z = dir*16 + batch
// LN + sigmoid fused inline: reads RAW pre from buf, stats are L2-resident.
__global__ __launch_bounds__(256) void scan_seg(const float* __restrict__ buf,
                                                const float2* __restrict__ stats,
                                                const float* __restrict__ gamma,
                                                const float* __restrict__ beta,
                                                float* __restrict__ segA,
                                                float* __restrict__ segB) {
    const int c   = blockIdx.x * 256 + threadIdx.x; // 0..511
    const int s   = blockIdx.y;
    const int dir = blockIdx.z >> 4;
    const int b   = blockIdx.z & 15;
    const int cg  = dir * HALF + c;
    const float ga0 = gamma[cg],        be0 = beta[cg];
    const float ga1 = gamma[cg + 1024], be1 = beta[cg + 1024];
    const size_t base = (size_t)b * N3 + cg;
    float Aacc = 1.0f, Bacc = 0.0f;
    if (dir == 0) {
#pragma unroll 4
        for (int i = 0; i < SEGLEN; ++i) {
            const int t = s * SEGLEN + i;
            const float2 st = stats[t * B_DIM + b];
            const size_t idx = (size_t)t * (B_DIM * N3) + base;
            const float g  = sigmoidf((buf[idx]        - st.x) * st.y * ga0 + be0);
            const float xv =          (buf[idx + 1024] - st.x) * st.y * ga1 + be1;
            const float a  = 1.0f - g;
            const float bv = g * xv;
            Aacc *= a;
            Bacc = a * Bacc + bv;
        }
    } else {
#pragma unroll 4
        for (int i = SEGLEN - 1; i >= 0; --i) {
            const int t = s * SEGLEN + i;
            const float2 st = stats[t * B_DIM + b];
            const size_t idx = (size_t)t * (B_DIM * N3) + base;
            const float g  = sigmoidf((buf[idx]        - st.x) * st.y * ga0 + be0);
            const float xv =          (buf[idx + 1024] - st.x) * st.y * ga1 + be1;
            const float a  = 1.0f - g;
            const float bv = g * xv;
            Aacc *= a;
            Bacc = a * Bacc + bv;
        }
    }
    const int seq = (dir * 16 + b) * HALF + c;
    segA[s * NSEQ + seq] = Aacc;
    segB[s * NSEQ + seq] = Bacc;
}

// exclusive carry scan across segments; segB[s] becomes initial h for segment s.
__global__ __launch_bounds__(256) void scan_carry(const float* __restrict__ segA,
                                                  float* __restrict__ segB) {
    const int seq = blockIdx.x * 256 + threadIdx.x;
    const int dir = seq >> 13;   // 8192 boundary, block-aligned -> uniform
    float h = 0.f;
    if (dir == 0) {
        for (int s = 0; s < SEG; ++s) {
            const float Av = segA[s * NSEQ + seq];
            const float Bv = segB[s * NSEQ + seq];
            segB[s * NSEQ + seq] = h;
            h = Av * h + Bv;
        }
    } else {
        for (int s = SEG - 1; s >= 0; --s) {
            const float Av = segA[s * NSEQ + seq];
            const float Bv = segB[s * NSEQ + seq];
            segB[s * NSEQ + seq] = h;
            h = Av * h + Bv;
        }
    }
}

// apply scan within segment, fused with LN+gates recompute and output combine
__global__ __launch_bounds__(256) void scan_apply(const float* __restrict__ buf,
                                                  const float2* __restrict__ stats,
                                                  const float* __restrict__ gamma,
                                                  const float* __restrict__ beta,
                                                  const float* __restrict__ segB,
                                                  const float* __restrict__ input,
                                                  float* __restrict__ out) {
    const int c   = blockIdx.x * 256 + threadIdx.x;
    const int s   = blockIdx.y;
    const int dir = blockIdx.z >> 4;
    const int b   = blockIdx.z & 15;
    const int cg  = dir * HALF + c;
    const int seq = (dir * 16 + b) * HALF + c;
    const float ga0 = gamma[cg],        be0 = beta[cg];
    const float ga1 = gamma[cg + 1024], be1 = beta[cg + 1024];
    const float ga2 = gamma[cg + 2048], be2 = beta[cg + 2048];
    float h = segB[s * NSEQ + seq];
    const size_t base3 = (size_t)b * N3 + cg;
    const size_t base1 = (size_t)b * D_DIM + cg;
    if (dir == 0) {
#pragma unroll 4
        for (int i = 0; i < SEGLEN; ++i) {
            const int t = s * SEGLEN + i;
            const float2 st = stats[t * B_DIM + b];
            const size_t i3 = (size_t)t * (B_DIM * N3) + base3;
            const size_t i1 = (size_t)t * (B_DIM * D_DIM) + base1;
            const float g  = sigmoidf((buf[i3]        - st.x) * st.y * ga0 + be0);
            const float xv =          (buf[i3 + 1024] - st.x) * st.y * ga1 + be1;
            const float hg = sigmoidf((buf[i3 + 2048] - st.x) * st.y * ga2 + be2);
            h = (1.0f - g) * h + g * xv;
            out[i1] = (1.0f - hg) * h + input[i1] * hg;
        }
    } else {
#pragma unroll 4
        for (int i = SEGLEN - 1; i >= 0; --i) {
            const int t = s * SEGLEN + i;
            const float2 st = stats[t * B_DIM + b];
            const size_t i3 = (size_t)t * (B_DIM * N3) + base3;
            const size_t i1 = (size_t)t * (B_DIM * D_DIM) + base1;
            const float g  = sigmoidf((buf[i3]        - st.x) * st.y * ga0 + be0);
            const float xv =          (buf[i3 + 1024] - st.x) * st.y * ga1 + be1;
            const float hg = sigmoidf((buf[i3 + 2048] - st.x) * st.y * ga2 + be2);
            h = (1.0f - g) * h + g * xv;
            out[i1] = (1.0f - hg) * h + input[i1] * hg;
        }
    }
}

extern "C" void kernel_launch(void* const* d_in, const int* in_sizes, int n_in,
                              void* d_out, int out_size, void* d_ws, size_t ws_size,
                              hipStream_t stream) {
    const float* input = (const float*)d_in[0];  // (T,B,D)
    const float* W     = (const float*)d_in[1];  // (D, 3D)
    const float* gamma = (const float*)d_in[2];  // (3D,)
    const float* beta  = (const float*)d_in[3];  // (3D,)
    float* out = (float*)d_out;                  // (T,B,D)

    char* ws = (char*)d_ws;
    const size_t szA   = (size_t)M_ROWS * D_DIM * 2;  // 64 MB bf16 A
    const size_t szWT  = (size_t)N3 * D_DIM * 2;      // 6 MB bf16 W^T
    const size_t szBuf = (size_t)M_ROWS * N3 * 4;     // 384 MB pre (raw, read-only after GEMM)
    const size_t szSeg = (size_t)SEG * NSEQ * 4;      // 2 MB each
    ushort* Abf  = (ushort*)ws;
    ushort* WT   = (ushort*)(ws + szA);
    float*  buf  = (float*)(ws + szA + szWT);
    float*  segA = (float*)(ws + szA + szWT + szBuf);
    float*  segB = (float*)(ws + szA + szWT + szBuf + szSeg);
    float2* partial = (float2*)(ws + szA + szWT + szBuf + 2 * szSeg);          // 6 MB
    float2* stats   = (float2*)(ws + szA + szWT + szBuf + 2 * szSeg
                                + (size_t)NBLK * M_ROWS * sizeof(float2));     // 256 KB

    cast_a<<<(M_ROWS * D_DIM) / (256 * 8), 256, 0, stream>>>(input, Abf);
    transpose_cast<<<dim3(N3 / 64, D_DIM / 64), 256, 0, stream>>>(W, WT);
    gemm_bf16<<<dim3(M_ROWS / 128, N3 / 128), 256, 0, stream>>>(Abf, WT, buf, partial);
    finalize_stats<<<M_ROWS / 256, 256, 0, stream>>>(partial, stats);
    scan_seg<<<dim3(2, SEG, 32), 256, 0, stream>>>(buf, stats, gamma, beta, segA, segB);
    scan_carry<<<NSEQ / 256, 256, 0, stream>>>(segA, segB);
    scan_apply<<<dim3(2, SEG, 32), 256, 0, stream>>>(buf, stats, gamma, beta, segB, input, out);
}

// Round 2
// 702.077 us; speedup vs baseline: 1.2819x; 1.1804x over previous
//
#include <hip/hip_runtime.h>
#include <hip/hip_bf16.h>
#include <cstdint>

#define T_DIM 2048
#define B_DIM 16
#define D_DIM 1024
#define N3    (3*D_DIM)          // 3072
#define M_ROWS (T_DIM*B_DIM)     // 32768
#define HALF  (D_DIM/2)          // 512
#define SEG    64
#define SEGLEN (T_DIM/SEG)       // 32
#define NSEQ  (2*B_DIM*HALF)     // 16384
#define NBLK  (N3/256)           // 12 column-blocks in GEMM grid
#define GEMM_GRID ((M_ROWS/256)*NBLK)  // 128*12 = 1536

typedef __attribute__((ext_vector_type(8))) short bf16x8;
typedef __attribute__((ext_vector_type(4))) float f32x4;

#define GLD_LDS16(g, l) __builtin_amdgcn_global_load_lds( \
    (const __attribute__((address_space(1))) void*)(g),   \
    (__attribute__((address_space(3))) void*)(l), 16, 0, 0)

__device__ __forceinline__ ushort f2bf(float x) {
    __hip_bfloat16 h = __float2bfloat16(x);
    return *reinterpret_cast<ushort*>(&h);
}

__device__ __forceinline__ float sigmoidf(float x) {
    return 1.0f / (1.0f + __expf(-x));
}

__device__ __forceinline__ float4 ln4(float4 v, float mu, float rs, float4 ga, float4 be) {
    float4 r;
    r.x = (v.x - mu) * rs * ga.x + be.x;
    r.y = (v.y - mu) * rs * ga.y + be.y;
    r.z = (v.z - mu) * rs * ga.z + be.z;
    r.w = (v.w - mu) * rs * ga.w + be.w;
    return r;
}

__device__ __forceinline__ float4 sig4(float4 v) {
    float4 r;
    r.x = sigmoidf(v.x); r.y = sigmoidf(v.y);
    r.z = sigmoidf(v.z); r.w = sigmoidf(v.w);
    return r;
}

// ---------------- cast input (fp32 -> bf16), 8 elems/thread ----------------
__global__ __launch_bounds__(256) void cast_a(const float* __restrict__ in,
                                              ushort* __restrict__ out) {
    const size_t i = (size_t)blockIdx.x * 256 + threadIdx.x; // handles 8 elems
    const float4* p = (const float4*)in + i * 2;
    float4 a = p[0], b = p[1];
    float f[8] = {a.x, a.y, a.z, a.w, b.x, b.y, b.z, b.w};
    ushort r[8];
#pragma unroll
    for (int j = 0; j < 8; ++j) r[j] = f2bf(f[j]);
    *(uint4*)(out + i * 8) = *(const uint4*)r;
}

// ---------------- W (1024 x 3072) -> W^T (3072 x 1024) bf16 ----------------
__global__ __launch_bounds__(256) void transpose_cast(const float* __restrict__ W,
                                                      ushort* __restrict__ WT) {
    __shared__ float tile[64][65];
    const int c0 = blockIdx.x * 64;  // N dim of W
    const int r0 = blockIdx.y * 64;  // K dim of W
    const int tr = threadIdx.x >> 6; // 0..3
    const int tc = threadIdx.x & 63;
#pragma unroll
    for (int i = 0; i < 16; ++i) {
        const int r = tr + i * 4;
        tile[r][tc] = W[(size_t)(r0 + r) * N3 + c0 + tc];
    }
    __syncthreads();
#pragma unroll
    for (int i = 0; i < 16; ++i) {
        const int r = tr + i * 4;  // row of WT = col of W
        WT[(size_t)(c0 + r) * D_DIM + r0 + tc] = f2bf(tile[tc][r]);
    }
}

// ---------------- GEMM: C(32768x3072) = A(32768x1024) * B, BT is N x K -----
// 256x256 tile, 8 waves (2M x 4N), BK=64, double-buffered 128 KB LDS.
// Counted-vmcnt pipeline: per K-tile {reads ks0 -> MFMA} {reads ks1 ->
// lgkmcnt(0) -> s_barrier -> stage(t+2 into freed buffer) -> MFMA ->
// vmcnt(8) -> s_barrier}. vmcnt never drains to 0 in the main loop (one
// full tile = 8 gloads stays in flight across barriers). Raw s_barrier +
// inline-asm waits; __syncthreads() would drain vmcnt(0) and kill the
// pipeline. XOR swizzle identical to the 128^2 version (measured 0 bank
// conflicts). Epilogue: C write + per-row (sum,sumsq) partial for LN.
__global__ __launch_bounds__(512, 2) void gemm_bf16(const ushort* __restrict__ A,
                                                    const ushort* __restrict__ BT,
                                                    float* __restrict__ C,
                                                    float2* __restrict__ partial) {
    const int K = D_DIM;
    const int N = N3;
    __shared__ ushort As[2][256 * 64];
    __shared__ ushort Bs[2][256 * 64];
    const int tid  = threadIdx.x;
    const int wave = tid >> 6;
    const int lane = tid & 63;

    // XCD-chunked swizzle (1536 % 8 == 0 -> bijective), then m-major so each
    // XCD's contiguous 12-block run shares one 512 KB A panel (L2 reuse).
    int bid = blockIdx.x;
    bid = (bid & 7) * (GEMM_GRID / 8) + (bid >> 3);
    const int m0    = (bid / NBLK) * 256;
    const int n_blk = bid % NBLK;
    const int n0    = n_blk * 256;

    const int wm = wave >> 2;        // 0..1
    const int wn = wave & 3;         // 0..3
    const int srow = lane >> 3;
    const int skc  = (((lane & 7) ^ srow) * 8);   // swizzled k-chunk (elems)

    f32x4 acc[8][4] = {};
    bf16x8 af[8], bfr[4];

    const int q  = lane >> 4;
    const int lm = lane & 15;
    const int sw = lm & 7;

    auto stage = [&](int t, int p) {
#pragma unroll
        for (int it = 0; it < 4; ++it) {
            const int rb = it * 64 + wave * 8;
            GLD_LDS16(A  + (size_t)(m0 + rb + srow) * K + t * 64 + skc, &As[p][rb * 64]);
            GLD_LDS16(BT + (size_t)(n0 + rb + srow) * K + t * 64 + skc, &Bs[p][rb * 64]);
        }
    };
    auto read_frags = [&](int p, int ks) {
        const int ch = ((ks * 4 + q) ^ sw) * 8;
#pragma unroll
        for (int m = 0; m < 8; ++m)
            af[m] = *(const bf16x8*)&As[p][(wm * 128 + m * 16 + lm) * 64 + ch];
#pragma unroll
        for (int n = 0; n < 4; ++n)
            bfr[n] = *(const bf16x8*)&Bs[p][(wn * 64 + n * 16 + lm) * 64 + ch];
    };
    auto do_mfma = [&]() {
        __builtin_amdgcn_s_setprio(1);
#pragma unroll
        for (int m = 0; m < 8; ++m)
#pragma unroll
            for (int n = 0; n < 4; ++n)
                acc[m][n] = __builtin_amdgcn_mfma_f32_16x16x32_bf16(af[m], bfr[n], acc[m][n], 0, 0, 0);
        __builtin_amdgcn_s_setprio(0);
    };

    // prologue: stage tiles 0,1; wait tile0 landed (8 of 16 outstanding)
    stage(0, 0);
    stage(1, 1);
    asm volatile("s_waitcnt vmcnt(8)" ::: "memory");
    __builtin_amdgcn_sched_barrier(0);
    __builtin_amdgcn_s_barrier();
    __builtin_amdgcn_sched_barrier(0);

    // main loop: tiles 0..13 (stages tiles 2..15)
#pragma unroll 2
    for (int t = 0; t < (K / 64) - 2; ++t) {
        const int p = t & 1;
        read_frags(p, 0);
        do_mfma();
        read_frags(p, 1);
        asm volatile("s_waitcnt lgkmcnt(0)" ::: "memory");   // my reads of buf[p] done
        __builtin_amdgcn_sched_barrier(0);
        __builtin_amdgcn_s_barrier();                        // everyone's reads done
        __builtin_amdgcn_sched_barrier(0);
        stage(t + 2, p);                                     // overwrite freed buffer
        do_mfma();
        asm volatile("s_waitcnt vmcnt(8)" ::: "memory");     // tile t+1 landed
        __builtin_amdgcn_sched_barrier(0);
        __builtin_amdgcn_s_barrier();
        __builtin_amdgcn_sched_barrier(0);
    }
    // tile 14 (no staging); drain tile 15's loads at the end
    read_frags(0, 0);
    do_mfma();
    read_frags(0, 1);
    do_mfma();
    asm volatile("s_waitcnt vmcnt(0)" ::: "memory");
    __builtin_amdgcn_sched_barrier(0);
    __builtin_amdgcn_s_barrier();
    __builtin_amdgcn_sched_barrier(0);
    // tile 15
    read_frags(1, 0);
    do_mfma();
    read_frags(1, 1);
    do_mfma();

    // ---- C write ----
#pragma unroll
    for (int m = 0; m < 8; ++m) {
        const int row = m0 + wm * 128 + m * 16 + q * 4;
#pragma unroll
        for (int n = 0; n < 4; ++n) {
            const int col = n0 + wn * 64 + n * 16 + lm;
            float* cp = C + (size_t)row * N + col;
#pragma unroll
            for (int r = 0; r < 4; ++r)
                cp[(size_t)r * N] = acc[m][n][r];
        }
    }

    // ---- per-row partial stats over this block's 256 columns ----
    float* sS  = (float*)&As[0][0];     // [wn][256 rows]
    float* sSS = sS + 1024;
#pragma unroll
    for (int m = 0; m < 8; ++m) {
#pragma unroll
        for (int r = 0; r < 4; ++r) {
            float s  = acc[m][0][r] + acc[m][1][r] + acc[m][2][r] + acc[m][3][r];
            float ss = acc[m][0][r] * acc[m][0][r] + acc[m][1][r] * acc[m][1][r]
                     + acc[m][2][r] * acc[m][2][r] + acc[m][3][r] * acc[m][3][r];
            s  += __shfl_xor(s, 1);  ss += __shfl_xor(ss, 1);
            s  += __shfl_xor(s, 2);  ss += __shfl_xor(ss, 2);
            s  += __shfl_xor(s, 4);  ss += __shfl_xor(ss, 4);
            s  += __shfl_xor(s, 8);  ss += __shfl_xor(ss, 8);
            if (lm == 0) {
                const int rl = wm * 128 + m * 16 + q * 4 + r;
                sS [wn * 256 + rl] = s;
                sSS[wn * 256 + rl] = ss;
            }
        }
    }
    __syncthreads();
    if (tid < 256) {
        const float S  = sS [tid] + sS [256 + tid] + sS [512 + tid] + sS [768 + tid];
        const float SS = sSS[tid] + sSS[256 + tid] + sSS[512 + tid] + sSS[768 + tid];
        partial[(size_t)n_blk * M_ROWS + m0 + tid] = make_float2(S, SS);
    }
}

// ---- combine 12 column-block partials -> per-row (mu, rstd) ---------------
__global__ __launch_bounds__(256) void finalize_stats(const float2* __restrict__ partial,
                                                      float2* __restrict__ stats) {
    const int row = blockIdx.x * 256 + threadIdx.x;
    float S = 0.f, SS = 0.f;
#pragma unroll
    for (int nb = 0; nb < NBLK; ++nb) {
        const float2 p = partial[(size_t)nb * M_ROWS + row];
        S += p.x; SS += p.y;
    }
    const float mu  = S * (1.0f / 3072.0f);
    const float var = SS * (1.0f / 3072.0f) - mu * mu;
    stats[row] = make_float2(mu, rsqrtf(var + 1e-5f));
}

// ---------------- segmented linear-recurrence scan (float4) ----------------
// grid (SEG, B_DIM), 256 threads; thread handles 4 consecutive channels.
// Threads 0..127 -> forward half (c 0..511), 128..255 -> backward half
// (c 512..1023): dir is wave-uniform. LN + sigmoid recomputed inline.
__global__ __launch_bounds__(256) void scan_seg(const float* __restrict__ buf,
                                                const float2* __restrict__ stats,
                                                const float* __restrict__ gamma,
                                                const float* __restrict__ beta,
                                                float* __restrict__ segA,
                                                float* __restrict__ segB) {
    const int tid = threadIdx.x;
    const int s   = blockIdx.x;
    const int b   = blockIdx.y;
    const int dir = tid >> 7;
    const int cg4 = tid * 4;                 // global channel base (0..1020)
    const float4 ga0 = *(const float4*)&gamma[cg4];
    const float4 be0 = *(const float4*)&beta [cg4];
    const float4 ga1 = *(const float4*)&gamma[cg4 + 1024];
    const float4 be1 = *(const float4*)&beta [cg4 + 1024];
    const size_t base = (size_t)b * N3 + cg4;
    float4 Aa = {1.f, 1.f, 1.f, 1.f};
    float4 Bb = {0.f, 0.f, 0.f, 0.f};

#define SEG_STEP(t)                                                         \
    {   const float2 st = stats[(t) * B_DIM + b];                           \
        const size_t idx = (size_t)(t) * (B_DIM * N3) + base;               \
        const float4 p0 = *(const float4*)&buf[idx];                        \
        const float4 p1 = *(const float4*)&buf[idx + 1024];                 \
        const float4 g  = sig4(ln4(p0, st.x, st.y, ga0, be0));              \
        const float4 xv = ln4(p1, st.x, st.y, ga1, be1);                    \
        Aa.x *= (1.f - g.x); Bb.x = (1.f - g.x) * Bb.x + g.x * xv.x;        \
        Aa.y *= (1.f - g.y); Bb.y = (1.f - g.y) * Bb.y + g.y * xv.y;        \
        Aa.z *= (1.f - g.z); Bb.z = (1.f - g.z) * Bb.z + g.z * xv.z;        \
        Aa.w *= (1.f - g.w); Bb.w = (1.f - g.w) * Bb.w + g.w * xv.w;        }

    if (dir == 0) {
#pragma unroll 4
        for (int i = 0; i < SEGLEN; ++i) SEG_STEP(s * SEGLEN + i);
    } else {
#pragma unroll 4
        for (int i = SEGLEN - 1; i >= 0; --i) SEG_STEP(s * SEGLEN + i);
    }
#undef SEG_STEP
    const int seq = (dir * 16 + b) * HALF + (cg4 - dir * 512);
    *(float4*)&segA[(size_t)s * NSEQ + seq] = Aa;
    *(float4*)&segB[(size_t)s * NSEQ + seq] = Bb;
}

// exclusive carry scan across segments (float4; 4 seqs/thread, same dir)
__global__ __launch_bounds__(256) void scan_carry(const float* __restrict__ segA,
                                                  float* __restrict__ segB) {
    const int seq4 = (blockIdx.x * 256 + threadIdx.x) * 4;
    const int dir  = seq4 >> 13;
    float4 h = {0.f, 0.f, 0.f, 0.f};
#define CARRY_STEP(s)                                                       \
    {   const float4 Av = *(const float4*)&segA[(size_t)(s) * NSEQ + seq4]; \
        float4* bp = (float4*)&segB[(size_t)(s) * NSEQ + seq4];             \
        const float4 Bv = *bp;                                              \
        *bp = h;                                                            \
        h.x = Av.x * h.x + Bv.x; h.y = Av.y * h.y + Bv.y;                   \
        h.z = Av.z * h.z + Bv.z; h.w = Av.w * h.w + Bv.w;                   }
    if (dir == 0) {
        for (int s = 0; s < SEG; ++s) CARRY_STEP(s);
    } else {
        for (int s = SEG - 1; s >= 0; --s) CARRY_STEP(s);
    }
#undef CARRY_STEP
}

// apply scan within segment, fused with LN+gates recompute and output combine
__global__ __launch_bounds__(256) void scan_apply(const float* __restrict__ buf,
                                                  const float2* __restrict__ stats,
                                                  const float* __restrict__ gamma,
                                                  const float* __restrict__ beta,
                                                  const float* __restrict__ segB,
                                                  const float* __restrict__ input,
                                                  float* __restrict__ out) {
    const int tid = threadIdx.x;
    const int s   = blockIdx.x;
    const int b   = blockIdx.y;
    const int dir = tid >> 7;
    const int cg4 = tid * 4;
    const float4 ga0 = *(const float4*)&gamma[cg4];
    const float4 be0 = *(const float4*)&beta [cg4];
    const float4 ga1 = *(const float4*)&gamma[cg4 + 1024];
    const float4 be1 = *(const float4*)&beta [cg4 + 1024];
    const float4 ga2 = *(const float4*)&gamma[cg4 + 2048];
    const float4 be2 = *(const float4*)&beta [cg4 + 2048];
    const int seq = (dir * 16 + b) * HALF + (cg4 - dir * 512);
    float4 h = *(const float4*)&segB[(size_t)s * NSEQ + seq];
    const size_t base3 = (size_t)b * N3 + cg4;
    const size_t base1 = (size_t)b * D_DIM + cg4;

#define APPLY_STEP(t)                                                       \
    {   const float2 st = stats[(t) * B_DIM + b];                           \
        const size_t i3 = (size_t)(t) * (B_DIM * N3) + base3;               \
        const size_t i1 = (size_t)(t) * (B_DIM * D_DIM) + base1;            \
        const float4 p0 = *(const float4*)&buf[i3];                         \
        const float4 p1 = *(const float4*)&buf[i3 + 1024];                  \
        const float4 p2 = *(const float4*)&buf[i3 + 2048];                  \
        const float4 iv = *(const float4*)&input[i1];                       \
        const float4 g  = sig4(ln4(p0, st.x, st.y, ga0, be0));              \
        const float4 xv = ln4(p1, st.x, st.y, ga1, be1);                    \
        const float4 hg = sig4(ln4(p2, st.x, st.y, ga2, be2));              \
        float4 o;                                                           \
        h.x = (1.f - g.x) * h.x + g.x * xv.x;                               \
        h.y = (1.f - g.y) * h.y + g.y * xv.y;                               \
        h.z = (1.f - g.z) * h.z + g.z * xv.z;                               \
        h.w = (1.f - g.w) * h.w + g.w * xv.w;                               \
        o.x = (1.f - hg.x) * h.x + iv.x * hg.x;                             \
        o.y = (1.f - hg.y) * h.y + iv.y * hg.y;                             \
        o.z = (1.f - hg.z) * h.z + iv.z * hg.z;                             \
        o.w = (1.f - hg.w) * h.w + iv.w * hg.w;                             \
        *(float4*)&out[i1] = o;                                             }

    if (dir == 0) {
#pragma unroll 4
        for (int i = 0; i < SEGLEN; ++i) APPLY_STEP(s * SEGLEN + i);
    } else {
#pragma unroll 4
        for (int i = SEGLEN - 1; i >= 0; --i) APPLY_STEP(s * SEGLEN + i);
    }
#undef APPLY_STEP
}

extern "C" void kernel_launch(void* const* d_in, const int* in_sizes, int n_in,
                              void* d_out, int out_size, void* d_ws, size_t ws_size,
                              hipStream_t stream) {
    const float* input = (const float*)d_in[0];  // (T,B,D)
    const float* W     = (const float*)d_in[1];  // (D, 3D)
    const float* gamma = (const float*)d_in[2];  // (3D,)
    const float* beta  = (const float*)d_in[3];  // (3D,)
    float* out = (float*)d_out;                  // (T,B,D)

    char* ws = (char*)d_ws;
    const size_t szA   = (size_t)M_ROWS * D_DIM * 2;  // 64 MB bf16 A
    const size_t szWT  = (size_t)N3 * D_DIM * 2;      // 6 MB bf16 W^T
    const size_t szBuf = (size_t)M_ROWS * N3 * 4;     // 384 MB pre (raw)
    ushort* Abf  = (ushort*)ws;
    ushort* WT   = (ushort*)(ws + szA);
    float*  buf  = (float*)(ws + szA + szWT);
    float2* partial = (float2*)(ws + szA + szWT + szBuf);                      // 3 MB
    float2* stats   = (float2*)((char*)partial + (size_t)NBLK * M_ROWS * 8);   // 256 KB
    // segA/segB alias the Abf region (dead after GEMM): 2 x 4 MB << 64 MB
    float*  segA = (float*)ws;
    float*  segB = segA + (size_t)SEG * NSEQ;

    cast_a<<<(M_ROWS * D_DIM) / (256 * 8), 256, 0, stream>>>(input, Abf);
    transpose_cast<<<dim3(N3 / 64, D_DIM / 64), 256, 0, stream>>>(W, WT);
    gemm_bf16<<<GEMM_GRID, 512, 0, stream>>>(Abf, WT, buf, partial);
    finalize_stats<<<M_ROWS / 256, 256, 0, stream>>>(partial, stats);
    scan_seg<<<dim3(SEG, B_DIM), 256, 0, stream>>>(buf, stats, gamma, beta, segA, segB);
    scan_carry<<<NSEQ / 1024, 256, 0, stream>>>(segA, segB);
    scan_apply<<<dim3(SEG, B_DIM), 256, 0, stream>>>(buf, stats, gamma, beta, segB, input, out);
}

// Round 5
// 662.625 us; speedup vs baseline: 1.3583x; 1.0595x over previous
//
#include <hip/hip_runtime.h>
#include <hip/hip_bf16.h>
#include <cstdint>

#define T_DIM 2048
#define B_DIM 16
#define D_DIM 1024
#define N3    (3*D_DIM)          // 3072
#define M_ROWS (T_DIM*B_DIM)     // 32768
#define HALF  (D_DIM/2)          // 512
#define SEG    128
#define SEGLEN (T_DIM/SEG)       // 16
#define NSEQ  (2*B_DIM*HALF)     // 16384
#define NBLK  (N3/256)           // 12 column-blocks in GEMM grid
#define GEMM_GRID ((M_ROWS/256)*NBLK)  // 128*12 = 1536

typedef __attribute__((ext_vector_type(8))) short bf16x8;
typedef __attribute__((ext_vector_type(4))) float f32x4;

#define GLD_LDS16(g, l) __builtin_amdgcn_global_load_lds( \
    (const __attribute__((address_space(1))) void*)(g),   \
    (__attribute__((address_space(3))) void*)(l), 16, 0, 0)

__device__ __forceinline__ ushort f2bf(float x) {
    __hip_bfloat16 h = __float2bfloat16(x);
    return *reinterpret_cast<ushort*>(&h);
}

__device__ __forceinline__ float sigmoidf(float x) {
    return 1.0f / (1.0f + __expf(-x));
}

__device__ __forceinline__ f32x4 ln4(f32x4 v, float mu, float rs, f32x4 ga, f32x4 be) {
    f32x4 r;
    r.x = (v.x - mu) * rs * ga.x + be.x;
    r.y = (v.y - mu) * rs * ga.y + be.y;
    r.z = (v.z - mu) * rs * ga.z + be.z;
    r.w = (v.w - mu) * rs * ga.w + be.w;
    return r;
}

__device__ __forceinline__ f32x4 sig4(f32x4 v) {
    f32x4 r;
    r.x = sigmoidf(v.x); r.y = sigmoidf(v.y);
    r.z = sigmoidf(v.z); r.w = sigmoidf(v.w);
    return r;
}

// ---------------- cast input (fp32 -> bf16), 8 elems/thread ----------------
__global__ __launch_bounds__(256) void cast_a(const float* __restrict__ in,
                                              ushort* __restrict__ out) {
    const size_t i = (size_t)blockIdx.x * 256 + threadIdx.x; // handles 8 elems
    const f32x4* p = (const f32x4*)in + i * 2;
    f32x4 a = p[0], b = p[1];
    float f[8] = {a.x, a.y, a.z, a.w, b.x, b.y, b.z, b.w};
    ushort r[8];
#pragma unroll
    for (int j = 0; j < 8; ++j) r[j] = f2bf(f[j]);
    *(uint4*)(out + i * 8) = *(const uint4*)r;
}

// ------- W (1024 x 3072) -> PB: MFMA-fragment-packed bf16 B operand --------
// PB chunk index idx = (g*32 + ks)*64 + lane, holding 8 bf16:
//   lane = q*16+lm  ->  WT row (g*16+lm) = W col,  K cols ks*32+q*8 .. +8
// A wave reading chunk base (g,ks) at its own lane gets exactly the
// mfma_f32_16x16x32_bf16 B fragment for rows g*16.. and k-chunk ks.
__global__ __launch_bounds__(256) void pack_b(const float* __restrict__ W,
                                              ushort* __restrict__ PB) {
    const int idx  = blockIdx.x * 256 + threadIdx.x;
    const int lane = idx & 63;
    const int gks  = idx >> 6;
    const int ks   = gks & 31;
    const int g    = gks >> 5;
    const int lm = lane & 15, q = lane >> 4;
    const int n  = g * 16 + lm;
    const int k0 = ks * 32 + q * 8;
    ushort r[8];
#pragma unroll
    for (int e = 0; e < 8; ++e) r[e] = f2bf(W[(size_t)(k0 + e) * N3 + n]);
    *(uint4*)&PB[(size_t)idx * 8] = *(const uint4*)r;
}

// ---------------- GEMM: C(32768x3072) = A(32768x1024) * B ------------------
// 256x256 tile, 8 waves (2M x 4N). B-frags come DIRECT from packed PB
// (L1/L2-resident, coalesced) -- B never touches LDS. A is staged into a
// 4-deep circular LDS buffer (4 x 32 KB) via global_load_lds, XOR-swizzled.
// Per tile t: stage A(t+2) -> buf[(t+2)&3]; prefetch B(t+1) -> regs;
// 4 quadrant phases x 16 MFMA; then ONE gate vmcnt(12) + s_barrier.
// Ledger: the 12 newest vmem ops at the gate are exactly this iter's
// stage(4)+B(8), so everything older -- stage(t+1), B(t) -- has landed.
// Distinct circular buffers eliminate the WAR that needed a second barrier.
__global__ __launch_bounds__(512, 2) void gemm_bf16(const ushort* __restrict__ A,
                                                    const ushort* __restrict__ PB,
                                                    float* __restrict__ C,
                                                    float2* __restrict__ partial) {
    const int K = D_DIM;
    const int N = N3;
    __shared__ ushort As[4][256 * 64];
    const int tid  = threadIdx.x;
    const int wave = tid >> 6;
    const int lane = tid & 63;

    // XCD-chunked swizzle (1536 % 8 == 0 -> bijective), m-major inside each
    // XCD so its 12-block n-runs share one A panel (L2 reuse).
    int bid = blockIdx.x;
    bid = (bid & 7) * (GEMM_GRID / 8) + (bid >> 3);
    const int m0    = (bid / NBLK) * 256;
    const int n_blk = bid % NBLK;
    const int n0    = n_blk * 256;

    const int wm = wave >> 2;        // 0..1
    const int wn = wave & 3;         // 0..3
    const int srow = lane >> 3;
    const int skc  = (((lane & 7) ^ srow) * 8);   // swizzled k-chunk (elems)

    const int q  = lane >> 4;
    const int lm = lane & 15;
    const int sw = lm & 7;
    const int ch0 = ((0 * 4 + q) ^ sw) * 8;       // k-subtile 0 chunk offset
    const int ch1 = ((1 * 4 + q) ^ sw) * 8;       // k-subtile 1 chunk offset
    const int gb  = (n0 >> 4) + wn * 4;           // B group base (16-row groups)

    f32x4 acc[8][4] = {};
    bf16x8 bA[8], bB[8];

    auto stageA = [&](int t) {
        const int ts = t > 15 ? 15 : t;
        const int p  = t & 3;
#pragma unroll
        for (int it = 0; it < 4; ++it) {
            const int rb = it * 64 + wave * 8;
            GLD_LDS16(A + (size_t)(m0 + rb + srow) * K + ts * 64 + skc, &As[p][rb * 64]);
        }
    };
    auto loadB = [&](int t, bf16x8* dst) {
        const int tb = t > 15 ? 15 : t;
#pragma unroll
        for (int n = 0; n < 4; ++n)
#pragma unroll
            for (int ks = 0; ks < 2; ++ks)
                dst[n * 2 + ks] = *(const bf16x8*)&PB[((((size_t)gb + n) * 32 + 2 * tb + ks) * 64 + lane) * 8];
    };
    auto TILE = [&](int t, bf16x8* bc, bf16x8* bn) {
        stageA(t + 2);                 // 4 vmem -> buf[(t+2)&3]
        loadB(t + 1, bn);              // 8 vmem -> regs for next tile
        const ushort* Ab = &As[t & 3][0];
#pragma unroll
        for (int mq = 0; mq < 4; ++mq) {
            const int r0 = (wm * 128 + (2 * mq) * 16 + lm) * 64;
            const int r1 = (wm * 128 + (2 * mq + 1) * 16 + lm) * 64;
            bf16x8 a00 = *(const bf16x8*)&Ab[r0 + ch0];
            bf16x8 a10 = *(const bf16x8*)&Ab[r1 + ch0];
            bf16x8 a01 = *(const bf16x8*)&Ab[r0 + ch1];
            bf16x8 a11 = *(const bf16x8*)&Ab[r1 + ch1];
            __builtin_amdgcn_s_setprio(1);
#pragma unroll
            for (int n = 0; n < 4; ++n) {
                acc[2 * mq][n]     = __builtin_amdgcn_mfma_f32_16x16x32_bf16(a00, bc[n * 2],     acc[2 * mq][n],     0, 0, 0);
                acc[2 * mq + 1][n] = __builtin_amdgcn_mfma_f32_16x16x32_bf16(a10, bc[n * 2],     acc[2 * mq + 1][n], 0, 0, 0);
                acc[2 * mq][n]     = __builtin_amdgcn_mfma_f32_16x16x32_bf16(a01, bc[n * 2 + 1], acc[2 * mq][n],     0, 0, 0);
                acc[2 * mq + 1][n] = __builtin_amdgcn_mfma_f32_16x16x32_bf16(a11, bc[n * 2 + 1], acc[2 * mq + 1][n], 0, 0, 0);
            }
            __builtin_amdgcn_s_setprio(0);
        }
        asm volatile("s_waitcnt vmcnt(12)" ::: "memory");  // stage(t+1)+B(t) landed
        __builtin_amdgcn_sched_barrier(0);
        __builtin_amdgcn_s_barrier();                      // all waves' stages landed
        __builtin_amdgcn_sched_barrier(0);
    };

    // prologue: stage tiles 0,1; B(0); gate tile0 (12 newest = stage(1)+B(0))
    stageA(0);
    stageA(1);
    loadB(0, bA);
    asm volatile("s_waitcnt vmcnt(12)" ::: "memory");
    __builtin_amdgcn_sched_barrier(0);
    __builtin_amdgcn_s_barrier();
    __builtin_amdgcn_sched_barrier(0);

#pragma unroll 1
    for (int tt = 0; tt < 8; ++tt) {
        TILE(2 * tt,     bA, bB);
        TILE(2 * tt + 1, bB, bA);
    }

    __syncthreads();   // drains vmcnt(0) incl. dummy tail stages; LDS now dead

    // ---- C write (nontemporal: streamed, no reuse before the scans) ----
#pragma unroll
    for (int m = 0; m < 8; ++m) {
        const int row = m0 + wm * 128 + m * 16 + q * 4;
#pragma unroll
        for (int n = 0; n < 4; ++n) {
            const int col = n0 + wn * 64 + n * 16 + lm;
            float* cp = C + (size_t)row * N + col;
#pragma unroll
            for (int r = 0; r < 4; ++r)
                __builtin_nontemporal_store(acc[m][n][r], cp + (size_t)r * N);
        }
    }

    // ---- per-row partial stats over this block's 256 columns ----
    float* sS  = (float*)&As[0][0];     // [wn][256 rows]
    float* sSS = sS + 1024;
#pragma unroll
    for (int m = 0; m < 8; ++m) {
#pragma unroll
        for (int r = 0; r < 4; ++r) {
            float s  = acc[m][0][r] + acc[m][1][r] + acc[m][2][r] + acc[m][3][r];
            float ss = acc[m][0][r] * acc[m][0][r] + acc[m][1][r] * acc[m][1][r]
                     + acc[m][2][r] * acc[m][2][r] + acc[m][3][r] * acc[m][3][r];
            s  += __shfl_xor(s, 1);  ss += __shfl_xor(ss, 1);
            s  += __shfl_xor(s, 2);  ss += __shfl_xor(ss, 2);
            s  += __shfl_xor(s, 4);  ss += __shfl_xor(ss, 4);
            s  += __shfl_xor(s, 8);  ss += __shfl_xor(ss, 8);
            if (lm == 0) {
                const int rl = wm * 128 + m * 16 + q * 4 + r;
                sS [wn * 256 + rl] = s;
                sSS[wn * 256 + rl] = ss;
            }
        }
    }
    __syncthreads();
    if (tid < 256) {
        const float S  = sS [tid] + sS [256 + tid] + sS [512 + tid] + sS [768 + tid];
        const float SS = sSS[tid] + sSS[256 + tid] + sSS[512 + tid] + sSS[768 + tid];
        partial[(size_t)n_blk * M_ROWS + m0 + tid] = make_float2(S, SS);
    }
}

// ---- combine 12 column-block partials -> per-row (mu, rstd) ---------------
__global__ __launch_bounds__(256) void finalize_stats(const float2* __restrict__ partial,
                                                      float2* __restrict__ stats) {
    const int row = blockIdx.x * 256 + threadIdx.x;
    float S = 0.f, SS = 0.f;
#pragma unroll
    for (int nb = 0; nb < NBLK; ++nb) {
        const float2 p = partial[(size_t)nb * M_ROWS + row];
        S += p.x; SS += p.y;
    }
    const float mu  = S * (1.0f / 3072.0f);
    const float var = SS * (1.0f / 3072.0f) - mu * mu;
    stats[row] = make_float2(mu, rsqrtf(var + 1e-5f));
}

// ---------------- segmented linear-recurrence scan (f32x4) -----------------
// grid (SEG=128, B_DIM): 2048 blocks (8/CU) for TLP. Threads 0..127 ->
// forward half, 128..255 -> backward half (wave-uniform dir). LN + sigmoid
// recomputed inline; buf is streamed with nontemporal loads.
__global__ __launch_bounds__(256) void scan_seg(const float* __restrict__ buf,
                                                const float2* __restrict__ stats,
                                                const float* __restrict__ gamma,
                                                const float* __restrict__ beta,
                                                float* __restrict__ segA,
                                                float* __restrict__ segB) {
    const int tid = threadIdx.x;
    const int s   = blockIdx.x;
    const int b   = blockIdx.y;
    const int dir = tid >> 7;
    const int cg4 = tid * 4;                 // global channel base (0..1020)
    const f32x4 ga0 = *(const f32x4*)&gamma[cg4];
    const f32x4 be0 = *(const f32x4*)&beta [cg4];
    const f32x4 ga1 = *(const f32x4*)&gamma[cg4 + 1024];
    const f32x4 be1 = *(const f32x4*)&beta [cg4 + 1024];
    const size_t base = (size_t)b * N3 + cg4;
    f32x4 Aa = {1.f, 1.f, 1.f, 1.f};
    f32x4 Bb = {0.f, 0.f, 0.f, 0.f};

#define SEG_STEP(t)                                                         \
    {   const float2 st = stats[(t) * B_DIM + b];                           \
        const size_t idx = (size_t)(t) * (B_DIM * N3) + base;               \
        const f32x4 p0 = __builtin_nontemporal_load((const f32x4*)&buf[idx]);        \
        const f32x4 p1 = __builtin_nontemporal_load((const f32x4*)&buf[idx + 1024]); \
        const f32x4 g  = sig4(ln4(p0, st.x, st.y, ga0, be0));               \
        const f32x4 xv = ln4(p1, st.x, st.y, ga1, be1);                     \
        Aa.x *= (1.f - g.x); Bb.x = (1.f - g.x) * Bb.x + g.x * xv.x;        \
        Aa.y *= (1.f - g.y); Bb.y = (1.f - g.y) * Bb.y + g.y * xv.y;        \
        Aa.z *= (1.f - g.z); Bb.z = (1.f - g.z) * Bb.z + g.z * xv.z;        \
        Aa.w *= (1.f - g.w); Bb.w = (1.f - g.w) * Bb.w + g.w * xv.w;        }

    if (dir == 0) {
#pragma unroll 8
        for (int i = 0; i < SEGLEN; ++i) SEG_STEP(s * SEGLEN + i);
    } else {
#pragma unroll 8
        for (int i = SEGLEN - 1; i >= 0; --i) SEG_STEP(s * SEGLEN + i);
    }
#undef SEG_STEP
    const int seq = (dir * 16 + b) * HALF + (cg4 - dir * 512);
    *(f32x4*)&segA[(size_t)s * NSEQ + seq] = Aa;
    *(f32x4*)&segB[(size_t)s * NSEQ + seq] = Bb;
}

// exclusive carry scan across segments (scalar, 64 blocks for latency TLP)
__global__ __launch_bounds__(256) void scan_carry(const float* __restrict__ segA,
                                                  float* __restrict__ segB) {
    const int seq = blockIdx.x * 256 + threadIdx.x;
    const int dir = seq >> 13;   // 8192 boundary, block-aligned -> uniform
    float h = 0.f;
    if (dir == 0) {
        for (int s = 0; s < SEG; ++s) {
            const float Av = segA[(size_t)s * NSEQ + seq];
            const float Bv = segB[(size_t)s * NSEQ + seq];
            segB[(size_t)s * NSEQ + seq] = h;
            h = Av * h + Bv;
        }
    } else {
        for (int s = SEG - 1; s >= 0; --s) {
            const float Av = segA[(size_t)s * NSEQ + seq];
            const float Bv = segB[(size_t)s * NSEQ + seq];
            segB[(size_t)s * NSEQ + seq] = h;
            h = Av * h + Bv;
        }
    }
}

// apply scan within segment, fused with LN+gates recompute and output combine
__global__ __launch_bounds__(256) void scan_apply(const float* __restrict__ buf,
                                                  const float2* __restrict__ stats,
                                                  const float* __restrict__ gamma,
                                                  const float* __restrict__ beta,
                                                  const float* __restrict__ segB,
                                                  const float* __restrict__ input,
                                                  float* __restrict__ out) {
    const int tid = threadIdx.x;
    const int s   = blockIdx.x;
    const int b   = blockIdx.y;
    const int dir = tid >> 7;
    const int cg4 = tid * 4;
    const f32x4 ga0 = *(const f32x4*)&gamma[cg4];
    const f32x4 be0 = *(const f32x4*)&beta [cg4];
    const f32x4 ga1 = *(const f32x4*)&gamma[cg4 + 1024];
    const f32x4 be1 = *(const f32x4*)&beta [cg4 + 1024];
    const f32x4 ga2 = *(const f32x4*)&gamma[cg4 + 2048];
    const f32x4 be2 = *(const f32x4*)&beta [cg4 + 2048];
    const int seq = (dir * 16 + b) * HALF + (cg4 - dir * 512);
    f32x4 h = *(const f32x4*)&segB[(size_t)s * NSEQ + seq];
    const size_t base3 = (size_t)b * N3 + cg4;
    const size_t base1 = (size_t)b * D_DIM + cg4;

#define APPLY_STEP(t)                                                       \
    {   const float2 st = stats[(t) * B_DIM + b];                           \
        const size_t i3 = (size_t)(t) * (B_DIM * N3) + base3;               \
        const size_t i1 = (size_t)(t) * (B_DIM * D_DIM) + base1;            \
        const f32x4 p0 = __builtin_nontemporal_load((const f32x4*)&buf[i3]);         \
        const f32x4 p1 = __builtin_nontemporal_load((const f32x4*)&buf[i3 + 1024]);  \
        const f32x4 p2 = __builtin_nontemporal_load((const f32x4*)&buf[i3 + 2048]);  \
        const f32x4 iv = *(const f32x4*)&input[i1];                         \
        const f32x4 g  = sig4(ln4(p0, st.x, st.y, ga0, be0));               \
        const f32x4 xv = ln4(p1, st.x, st.y, ga1, be1);                     \
        const f32x4 hg = sig4(ln4(p2, st.x, st.y, ga2, be2));               \
        f32x4 o;                                                            \
        h.x = (1.f - g.x) * h.x + g.x * xv.x;                               \
        h.y = (1.f - g.y) * h.y + g.y * xv.y;                               \
        h.z = (1.f - g.z) * h.z + g.z * xv.z;                               \
        h.w = (1.f - g.w) * h.w + g.w * xv.w;                               \
        o.x = (1.f - hg.x) * h.x + iv.x * hg.x;                             \
        o.y = (1.f - hg.y) * h.y + iv.y * hg.y;                             \
        o.z = (1.f - hg.z) * h.z + iv.z * hg.z;                             \
        o.w = (1.f - hg.w) * h.w + iv.w * hg.w;                             \
        __builtin_nontemporal_store(o, (f32x4*)&out[i1]);                   }

    if (dir == 0) {
#pragma unroll 8
        for (int i = 0; i < SEGLEN; ++i) APPLY_STEP(s * SEGLEN + i);
    } else {
#pragma unroll 8
        for (int i = SEGLEN - 1; i >= 0; --i) APPLY_STEP(s * SEGLEN + i);
    }
#undef APPLY_STEP
}

extern "C" void kernel_launch(void* const* d_in, const int* in_sizes, int n_in,
                              void* d_out, int out_size, void* d_ws, size_t ws_size,
                              hipStream_t stream) {
    const float* input = (const float*)d_in[0];  // (T,B,D)
    const float* W     = (const float*)d_in[1];  // (D, 3D)
    const float* gamma = (const float*)d_in[2];  // (3D,)
    const float* beta  = (const float*)d_in[3];  // (3D,)
    float* out = (float*)d_out;                  // (T,B,D)

    char* ws = (char*)d_ws;
    const size_t szA   = (size_t)M_ROWS * D_DIM * 2;  // 64 MB bf16 A
    const size_t szPB  = (size_t)N3 * D_DIM * 2;      // 6 MB packed B
    const size_t szBuf = (size_t)M_ROWS * N3 * 4;     // 384 MB pre (raw)
    ushort* Abf  = (ushort*)ws;
    ushort* PB   = (ushort*)(ws + szA);
    float*  buf  = (float*)(ws + szA + szPB);
    float2* partial = (float2*)(ws + szA + szPB + szBuf);                      // 3 MB
    float2* stats   = (float2*)((char*)partial + (size_t)NBLK * M_ROWS * 8);   // 256 KB
    // segA/segB alias the Abf region (dead after GEMM): 2 x 8 MB << 64 MB
    float*  segA = (float*)ws;
    float*  segB = segA + (size_t)SEG * NSEQ;

    cast_a<<<(M_ROWS * D_DIM) / (256 * 8), 256, 0, stream>>>(input, Abf);
    pack_b<<<(N3 / 16) * 32 * 64 / 256, 256, 0, stream>>>(W, PB);
    gemm_bf16<<<GEMM_GRID, 512, 0, stream>>>(Abf, PB, buf, partial);
    finalize_stats<<<M_ROWS / 256, 256, 0, stream>>>(partial, stats);
    scan_seg<<<dim3(SEG, B_DIM), 256, 0, stream>>>(buf, stats, gamma, beta, segA, segB);
    scan_carry<<<NSEQ / 256, 256, 0, stream>>>(segA, segB);
    scan_apply<<<dim3(SEG, B_DIM), 256, 0, stream>>>(buf, stats, gamma, beta, segB, input, out);
}